// Round 1
// baseline (4623.385 us; speedup 1.0000x reference)
//
#include <hip/hip_runtime.h>
#include <hip/hip_bf16.h>

#define NLAYER 3
#define BB 16
#define DD 1024
#define HH 16
#define HDIM 64
#define TPAST 1023
#define TTOT 1024
#define SENC 1024
#define FFD 4096
#define VOUT 20
#define ASCALE 0.125f
#define LNEPS 1e-5f

__device__ __forceinline__ float bf2f(unsigned short u) {
    union { unsigned int i; float f; } c; c.i = ((unsigned int)u) << 16; return c.f;
}
__device__ __forceinline__ unsigned short f2bf(float f) {
    union { float f; unsigned int i; } c; c.f = f;
    unsigned int x = c.i;
    unsigned int r = (x + 0x7fffu + ((x >> 16) & 1u)) >> 16;
    return (unsigned short)r;
}

// ---------------------------------------------------------------------------
// C_bf16[M=16384, N=1024] = A[16384,1024] @ W[1024,1024] + bias[N]
// 64x64 tile, 256 threads, 4x4 microtile, K-tile 16. LDS pitch 68 (pad).
// ---------------------------------------------------------------------------
__global__ __launch_bounds__(256) void gemm_big(
    const float* __restrict__ A, const float* __restrict__ W,
    const float* __restrict__ bias, unsigned short* __restrict__ C) {
    const int N = DD, K = DD;
    __shared__ __align__(16) float As[16 * 68];
    __shared__ __align__(16) float Ws[16 * 68];
    const int tid = threadIdx.x;
    const int tx = tid & 15, ty = tid >> 4;
    const int m0 = blockIdx.y * 64, n0 = blockIdx.x * 64;
    float acc[4][4] = {};
    const int ka = tid & 15, ma = tid >> 4;   // A-tile load mapping
    const int nw = tid & 63, kw = tid >> 6;   // W-tile load mapping
    for (int k0 = 0; k0 < K; k0 += 16) {
#pragma unroll
        for (int it = 0; it < 4; ++it)
            As[ka * 68 + ma + it * 16] = A[(size_t)(m0 + ma + it * 16) * K + k0 + ka];
#pragma unroll
        for (int it = 0; it < 4; ++it)
            Ws[(kw + it * 4) * 68 + nw] = W[(size_t)(k0 + kw + it * 4) * N + n0 + nw];
        __syncthreads();
#pragma unroll
        for (int kk = 0; kk < 16; ++kk) {
            float4 a4 = *(const float4*)&As[kk * 68 + ty * 4];
            float4 w4 = *(const float4*)&Ws[kk * 68 + tx * 4];
            float av[4] = {a4.x, a4.y, a4.z, a4.w};
            float wv[4] = {w4.x, w4.y, w4.z, w4.w};
#pragma unroll
            for (int i = 0; i < 4; ++i)
#pragma unroll
                for (int j = 0; j < 4; ++j)
                    acc[i][j] = fmaf(av[i], wv[j], acc[i][j]);
        }
        __syncthreads();
    }
#pragma unroll
    for (int i = 0; i < 4; ++i) {
        const int m = m0 + ty * 4 + i;
#pragma unroll
        for (int j = 0; j < 4; ++j) {
            const int n = n0 + tx * 4 + j;
            C[(size_t)m * N + n] = f2bf(acc[i][j] + bias[n]);
        }
    }
}

// ---------------------------------------------------------------------------
// Cacc[16, N] += X[16, K-slice] @ W[K-slice, N]   (atomic, C pre-zeroed)
// block = 64 threads (one wave), each owns one n-column; K-slice = 128.
// ---------------------------------------------------------------------------
#define KSL 128
__global__ __launch_bounds__(64) void gemm16(
    const float* __restrict__ X, const float* __restrict__ W,
    float* __restrict__ Cacc, int K, int N) {
    __shared__ __align__(16) float xs[16][KSL];
    const int tid = threadIdx.x;
    const int n = blockIdx.x * 64 + tid;
    const int k0 = blockIdx.y * KSL;
    for (int idx = tid; idx < 16 * KSL; idx += 64) {
        int b = idx >> 7;           // KSL == 128
        int k = idx & (KSL - 1);
        xs[b][k] = X[(size_t)b * K + k0 + k];
    }
    __syncthreads();
    float acc[16] = {};
    for (int k = 0; k < KSL; k += 4) {
        const float* wp = W + (size_t)(k0 + k) * N + n;
        float w0 = wp[0], w1 = wp[N], w2 = wp[2 * (size_t)N], w3 = wp[3 * (size_t)N];
#pragma unroll
        for (int b = 0; b < 16; ++b) {
            float4 xv = *(const float4*)&xs[b][k];
            acc[b] = fmaf(xv.x, w0, fmaf(xv.y, w1, fmaf(xv.z, w2, fmaf(xv.w, w3, acc[b]))));
        }
    }
#pragma unroll
    for (int b = 0; b < 16; ++b)
        atomicAdd(&Cacc[(size_t)b * N + n], acc[b]);
}

// ---------------------------------------------------------------------------
// Self-attention, one block per (h, b). Keys: cache[0..1022] + (k_new+bk).
// ---------------------------------------------------------------------------
__global__ __launch_bounds__(256) void attn_self(
    const float* __restrict__ q_raw, const float* __restrict__ bq,
    const float* __restrict__ kcache, const float* __restrict__ k_new,
    const float* __restrict__ bk,
    const float* __restrict__ vcache, const float* __restrict__ v_new,
    const float* __restrict__ bv, float* __restrict__ out) {
    const int h = blockIdx.x, b = blockIdx.y;
    const int tid = threadIdx.x;
    __shared__ __align__(16) float q[64];
    __shared__ float bks[64], bvs[64];
    __shared__ float sc[TTOT];
    __shared__ float red[256];
    if (tid < 64) {
        q[tid] = q_raw[b * DD + h * 64 + tid] + bq[h * 64 + tid];
        bks[tid] = bk[h * 64 + tid];
        bvs[tid] = bv[h * 64 + tid];
    }
    __syncthreads();
    const size_t bh = (size_t)(b * HH + h);
    for (int t = tid; t < TTOT; t += 256) {
        float dot = 0.f;
        if (t < TPAST) {
            const float4* kr = (const float4*)(kcache + (bh * TPAST + t) * HDIM);
            const float4* q4 = (const float4*)q;
#pragma unroll
            for (int i = 0; i < 16; ++i) {
                float4 kv = kr[i], qv = q4[i];
                dot += qv.x * kv.x + qv.y * kv.y + qv.z * kv.z + qv.w * kv.w;
            }
        } else {
            for (int i = 0; i < 64; ++i)
                dot += q[i] * (k_new[b * DD + h * 64 + i] + bks[i]);
        }
        sc[t] = dot * ASCALE;
    }
    __syncthreads();
    float lm = -1e30f;
    for (int t = tid; t < TTOT; t += 256) lm = fmaxf(lm, sc[t]);
    red[tid] = lm; __syncthreads();
    for (int s = 128; s > 0; s >>= 1) { if (tid < s) red[tid] = fmaxf(red[tid], red[tid + s]); __syncthreads(); }
    const float mx = red[0];
    __syncthreads();
    float ls = 0.f;
    for (int t = tid; t < TTOT; t += 256) { float p = __expf(sc[t] - mx); sc[t] = p; ls += p; }
    red[tid] = ls; __syncthreads();
    for (int s = 128; s > 0; s >>= 1) { if (tid < s) red[tid] += red[tid + s]; __syncthreads(); }
    const float inv = 1.0f / red[0];
    __syncthreads();
    const int hd = tid & 63, part = tid >> 6;
    float acc = 0.f;
    for (int t = part; t < TTOT; t += 4) {
        float v;
        if (t < TPAST) v = vcache[(bh * TPAST + t) * HDIM + hd];
        else           v = v_new[b * DD + h * 64 + hd] + bvs[hd];
        acc += sc[t] * v;
    }
    red[tid] = acc; __syncthreads();
    if (tid < 64)
        out[b * DD + h * 64 + tid] =
            (red[tid] + red[tid + 64] + red[tid + 128] + red[tid + 192]) * inv;
}

// ---------------------------------------------------------------------------
// Cross-attention vs precomputed bf16 Kc/Vc (biases already baked in).
// ---------------------------------------------------------------------------
__global__ __launch_bounds__(256) void attn_cross(
    const float* __restrict__ q_raw, const float* __restrict__ bq,
    const unsigned short* __restrict__ Kc, const unsigned short* __restrict__ Vc,
    float* __restrict__ out) {
    const int h = blockIdx.x, b = blockIdx.y;
    const int tid = threadIdx.x;
    __shared__ __align__(16) float q[64];
    __shared__ float sc[SENC];
    __shared__ float red[256];
    if (tid < 64)
        q[tid] = q_raw[b * DD + h * 64 + tid] + bq[h * 64 + tid];
    __syncthreads();
    for (int s = tid; s < SENC; s += 256) {
        const uint4* kr = (const uint4*)(Kc + ((size_t)(b * SENC + s)) * DD + h * HDIM);
        float dot = 0.f;
#pragma unroll
        for (int i = 0; i < 8; ++i) {
            uint4 u = kr[i];
            dot += q[i * 8 + 0] * bf2f((unsigned short)u.x) + q[i * 8 + 1] * bf2f((unsigned short)(u.x >> 16));
            dot += q[i * 8 + 2] * bf2f((unsigned short)u.y) + q[i * 8 + 3] * bf2f((unsigned short)(u.y >> 16));
            dot += q[i * 8 + 4] * bf2f((unsigned short)u.z) + q[i * 8 + 5] * bf2f((unsigned short)(u.z >> 16));
            dot += q[i * 8 + 6] * bf2f((unsigned short)u.w) + q[i * 8 + 7] * bf2f((unsigned short)(u.w >> 16));
        }
        sc[s] = dot * ASCALE;
    }
    __syncthreads();
    float lm = -1e30f;
    for (int t = tid; t < SENC; t += 256) lm = fmaxf(lm, sc[t]);
    red[tid] = lm; __syncthreads();
    for (int s = 128; s > 0; s >>= 1) { if (tid < s) red[tid] = fmaxf(red[tid], red[tid + s]); __syncthreads(); }
    const float mx = red[0];
    __syncthreads();
    float ls = 0.f;
    for (int t = tid; t < SENC; t += 256) { float p = __expf(sc[t] - mx); sc[t] = p; ls += p; }
    red[tid] = ls; __syncthreads();
    for (int s = 128; s > 0; s >>= 1) { if (tid < s) red[tid] += red[tid + s]; __syncthreads(); }
    const float inv = 1.0f / red[0];
    __syncthreads();
    const int hd = tid & 63, part = tid >> 6;
    float acc = 0.f;
    for (int t = part; t < SENC; t += 4)
        acc += sc[t] * bf2f(Vc[((size_t)(b * SENC + t)) * DD + h * HDIM + hd]);
    red[tid] = acc; __syncthreads();
    if (tid < 64)
        out[b * DD + h * 64 + tid] =
            (red[tid] + red[tid + 64] + red[tid + 128] + red[tid + 192]) * inv;
}

// ---------------------------------------------------------------------------
// x[b,:] = LN(x[b,:] + a[b,:] + abias) * g + bb   (one block per b)
// ---------------------------------------------------------------------------
__global__ __launch_bounds__(256) void ln_kernel(
    float* __restrict__ x, const float* __restrict__ a,
    const float* __restrict__ ab, const float* __restrict__ g,
    const float* __restrict__ bb) {
    const int b = blockIdx.x, tid = threadIdx.x;
    __shared__ float buf[DD];
    __shared__ float red[256];
    float ls = 0.f, lq = 0.f;
    for (int i = tid; i < DD; i += 256) {
        float v = x[b * DD + i] + a[b * DD + i] + ab[i];
        buf[i] = v; ls += v; lq += v * v;
    }
    red[tid] = ls; __syncthreads();
    for (int s = 128; s > 0; s >>= 1) { if (tid < s) red[tid] += red[tid + s]; __syncthreads(); }
    const float mean = red[0] * (1.0f / DD);
    __syncthreads();
    red[tid] = lq; __syncthreads();
    for (int s = 128; s > 0; s >>= 1) { if (tid < s) red[tid] += red[tid + s]; __syncthreads(); }
    const float var = red[0] * (1.0f / DD) - mean * mean;
    const float rstd = rsqrtf(var + LNEPS);
    for (int i = tid; i < DD; i += 256)
        x[b * DD + i] = (buf[i] - mean) * rstd * g[i] + bb[i];
}

__global__ __launch_bounds__(256) void relu_bias(
    const float* __restrict__ raw, const float* __restrict__ b1,
    float* __restrict__ out) {
    for (int i = blockIdx.x * 256 + threadIdx.x; i < BB * FFD; i += gridDim.x * 256)
        out[i] = fmaxf(0.f, raw[i] + b1[i & (FFD - 1)]);
}

// one block (64 threads) per (b, v) output logit
__global__ __launch_bounds__(64) void logits_kernel(
    const float* __restrict__ x, const float* __restrict__ w_out,
    const float* __restrict__ b_out, float* __restrict__ out) {
    const int b = blockIdx.x / VOUT, v = blockIdx.x % VOUT;
    const int tid = threadIdx.x;
    float acc = 0.f;
    for (int k = tid; k < DD; k += 64)
        acc += x[b * DD + k] * w_out[(size_t)k * VOUT + v];
    for (int s = 32; s > 0; s >>= 1) acc += __shfl_down(acc, s);
    if (tid == 0) out[b * VOUT + v] = acc + b_out[v];
}

extern "C" void kernel_launch(void* const* d_in, const int* in_sizes, int n_in,
                              void* d_out, int out_size, void* d_ws, size_t ws_size,
                              hipStream_t stream) {
    const float* x_in    = (const float*)d_in[0];
    const float* enc     = (const float*)d_in[1];
    const float* k_cache = (const float*)d_in[2];
    const float* v_cache = (const float*)d_in[3];
    const float* wq_s = (const float*)d_in[4];  const float* bq_s = (const float*)d_in[5];
    const float* wk_s = (const float*)d_in[6];  const float* bk_s = (const float*)d_in[7];
    const float* wv_s = (const float*)d_in[8];  const float* bv_s = (const float*)d_in[9];
    const float* wo_s = (const float*)d_in[10]; const float* bo_s = (const float*)d_in[11];
    const float* wq_c = (const float*)d_in[12]; const float* bq_c = (const float*)d_in[13];
    const float* wk_c = (const float*)d_in[14]; const float* bk_c = (const float*)d_in[15];
    const float* wv_c = (const float*)d_in[16]; const float* bv_c = (const float*)d_in[17];
    const float* wo_c = (const float*)d_in[18]; const float* bo_c = (const float*)d_in[19];
    const float* w1 = (const float*)d_in[20];   const float* b1 = (const float*)d_in[21];
    const float* w2 = (const float*)d_in[22];   const float* b2 = (const float*)d_in[23];
    const float* ln1_g = (const float*)d_in[24]; const float* ln1_b = (const float*)d_in[25];
    const float* ln2_g = (const float*)d_in[26]; const float* ln2_b = (const float*)d_in[27];
    const float* ln3_g = (const float*)d_in[28]; const float* ln3_b = (const float*)d_in[29];
    const float* w_out = (const float*)d_in[30]; const float* b_out = (const float*)d_in[31];
    float* out = (float*)d_out;

    float* ws = (float*)d_ws;
    float* x_buf  = ws;            // 16384
    float* mm_q   = ws + 16384;    // 16384
    float* mm_k   = ws + 32768;    // 16384
    float* mm_v   = ws + 49152;    // 16384
    float* attn_o = ws + 65536;    // 16384
    float* mm_p   = ws + 81920;    // 16384
    float* mm_h1  = ws + 98304;    // 65536
    float* h1a    = ws + 163840;   // 65536
    unsigned short* Kc = (unsigned short*)(ws + 229376);
    unsigned short* Vc = Kc + (size_t)BB * SENC * DD;

    hipMemcpyAsync(x_buf, x_in, (size_t)BB * DD * sizeof(float),
                   hipMemcpyDeviceToDevice, stream);

    const dim3 gBig(DD / 64, (BB * SENC) / 64);   // 16 x 256
    const dim3 gAttn(HH, BB);

    for (int l = 0; l < NLAYER; ++l) {
        const size_t oM = (size_t)l * DD * DD;
        const size_t oV = (size_t)l * DD;
        const size_t oC = (size_t)l * BB * HH * TPAST * HDIM;

        // cross-attn K/V projections for this layer (bias baked in)
        gemm_big<<<gBig, 256, 0, stream>>>(enc, wk_c + oM, bk_c + oV, Kc);
        gemm_big<<<gBig, 256, 0, stream>>>(enc, wv_c + oM, bv_c + oV, Vc);

        // ---- self attention ----
        hipMemsetAsync(mm_q, 0, 3 * (size_t)BB * DD * sizeof(float), stream);
        gemm16<<<dim3(DD / 64, DD / KSL), 64, 0, stream>>>(x_buf, wq_s + oM, mm_q, DD, DD);
        gemm16<<<dim3(DD / 64, DD / KSL), 64, 0, stream>>>(x_buf, wk_s + oM, mm_k, DD, DD);
        gemm16<<<dim3(DD / 64, DD / KSL), 64, 0, stream>>>(x_buf, wv_s + oM, mm_v, DD, DD);
        attn_self<<<gAttn, 256, 0, stream>>>(mm_q, bq_s + oV, k_cache + oC, mm_k,
                                             bk_s + oV, v_cache + oC, mm_v, bv_s + oV,
                                             attn_o);
        hipMemsetAsync(mm_p, 0, (size_t)BB * DD * sizeof(float), stream);
        gemm16<<<dim3(DD / 64, DD / KSL), 64, 0, stream>>>(attn_o, wo_s + oM, mm_p, DD, DD);
        ln_kernel<<<BB, 256, 0, stream>>>(x_buf, mm_p, bo_s + oV, ln1_g + oV, ln1_b + oV);

        // ---- cross attention ----
        hipMemsetAsync(mm_q, 0, (size_t)BB * DD * sizeof(float), stream);
        gemm16<<<dim3(DD / 64, DD / KSL), 64, 0, stream>>>(x_buf, wq_c + oM, mm_q, DD, DD);
        attn_cross<<<gAttn, 256, 0, stream>>>(mm_q, bq_c + oV, Kc, Vc, attn_o);
        hipMemsetAsync(mm_p, 0, (size_t)BB * DD * sizeof(float), stream);
        gemm16<<<dim3(DD / 64, DD / KSL), 64, 0, stream>>>(attn_o, wo_c + oM, mm_p, DD, DD);
        ln_kernel<<<BB, 256, 0, stream>>>(x_buf, mm_p, bo_c + oV, ln2_g + oV, ln2_b + oV);

        // ---- FFN ----
        hipMemsetAsync(mm_h1, 0, (size_t)BB * FFD * sizeof(float), stream);
        gemm16<<<dim3(FFD / 64, DD / KSL), 64, 0, stream>>>(x_buf, w1 + (size_t)l * DD * FFD,
                                                            mm_h1, DD, FFD);
        relu_bias<<<64, 256, 0, stream>>>(mm_h1, b1 + (size_t)l * FFD, h1a);
        hipMemsetAsync(mm_p, 0, (size_t)BB * DD * sizeof(float), stream);
        gemm16<<<dim3(DD / 64, FFD / KSL), 64, 0, stream>>>(h1a, w2 + (size_t)l * FFD * DD,
                                                            mm_p, FFD, DD);
        ln_kernel<<<BB, 256, 0, stream>>>(x_buf, mm_p, b2 + oV, ln3_g + oV, ln3_b + oV);
    }

    logits_kernel<<<BB * VOUT, 64, 0, stream>>>(x_buf, w_out, b_out, out);
}

// Round 2
// 2257.060 us; speedup vs baseline: 2.0484x; 2.0484x over previous
//
#include <hip/hip_runtime.h>
#include <hip/hip_bf16.h>

#define NLAYER 3
#define BB 16
#define DD 1024
#define HH 16
#define HDIM 64
#define TPAST 1023
#define TTOT 1024
#define SENC 1024
#define FFD 4096
#define VOUT 20
#define ASCALE 0.125f
#define LNEPS 1e-5f

#define GLP(p) ((const __attribute__((address_space(1))) unsigned int*)(p))
#define LDP(p) ((__attribute__((address_space(3))) unsigned int*)(p))

typedef __attribute__((ext_vector_type(8))) short bf16x8;
typedef __attribute__((ext_vector_type(4))) float f32x4;

__device__ __forceinline__ float bf2f(unsigned short u) {
    union { unsigned int i; float f; } c; c.i = ((unsigned int)u) << 16; return c.f;
}
__device__ __forceinline__ unsigned short f2bf(float f) {
    union { float f; unsigned int i; } c; c.f = f;
    unsigned int x = c.i;
    unsigned int r = (x + 0x7fffu + ((x >> 16) & 1u)) >> 16;
    return (unsigned short)r;
}

// ---------------------------------------------------------------------------
// fp32 -> bf16 convert (vectorized by 4)
// ---------------------------------------------------------------------------
__global__ __launch_bounds__(256) void cvt_bf16x4(
    const float* __restrict__ in, unsigned short* __restrict__ out, int n4) {
    int i = blockIdx.x * 256 + threadIdx.x;
    if (i < n4) {
        float4 v = ((const float4*)in)[i];
        ushort4 o;
        o.x = f2bf(v.x); o.y = f2bf(v.y); o.z = f2bf(v.z); o.w = f2bf(v.w);
        ((ushort4*)out)[i] = o;
    }
}

// ---------------------------------------------------------------------------
// W[K=1024][N=1024] fp32 -> Wt[N][K] bf16 (tile transpose through LDS)
// ---------------------------------------------------------------------------
__global__ __launch_bounds__(256) void wt_bf16(
    const float* __restrict__ W, unsigned short* __restrict__ Wt) {
    __shared__ float ts[64][65];
    const int tid = threadIdx.x;
    const int k0 = blockIdx.y * 64, n0 = blockIdx.x * 64;
#pragma unroll
    for (int p = 0; p < 16; ++p) {
        int idx = p * 256 + tid;
        int r = idx >> 6, c = idx & 63;
        ts[r][c] = W[(size_t)(k0 + r) * DD + n0 + c];
    }
    __syncthreads();
#pragma unroll
    for (int p = 0; p < 16; ++p) {
        int idx = p * 256 + tid;
        int nn = idx >> 6, kk = idx & 63;
        Wt[(size_t)(n0 + nn) * DD + k0 + kk] = f2bf(ts[kk][nn]);
    }
}

// ---------------------------------------------------------------------------
// C_bf16[M,N] = A_bf16[M,K] @ Bt_bf16[N,K]^T + bias   (M=16384, N=K=1024)
// 128x128 tile, 256 thr (4 waves, 2x2 of 64x64), BK=32, 16x16x32 bf16 MFMA,
// global_load_lds width-16 staging (m97 structure).
// ---------------------------------------------------------------------------
__global__ __launch_bounds__(256) void gemm_mfma_bt(
    const unsigned short* __restrict__ A, const unsigned short* __restrict__ Bt,
    const float* __restrict__ bias, unsigned short* __restrict__ C) {
    const int K = DD, N = DD;
    __shared__ __align__(16) unsigned short As[128 * 32];
    __shared__ __align__(16) unsigned short Bs[128 * 32];
    const int tid = threadIdx.x;
    const int w = tid >> 6, l = tid & 63;
    const int m0 = blockIdx.y * 128, n0 = blockIdx.x * 128;
    const int wm = (w >> 1) * 64, wn = (w & 1) * 64;
    const int lm = l & 15, q = l >> 4;
    f32x4 acc[4][4] = {};

    // staging: chunk c = w*128 + j*64 + l  ->  LDS ushort offset c*8
    const int c0 = w * 128 + l;
    const int c1 = c0 + 64;
    const unsigned short* Ag0 = A + (size_t)(m0 + (c0 >> 2)) * K + (c0 & 3) * 8;
    const unsigned short* Ag1 = A + (size_t)(m0 + (c1 >> 2)) * K + (c1 & 3) * 8;
    const unsigned short* Bg0 = Bt + (size_t)(n0 + (c0 >> 2)) * K + (c0 & 3) * 8;
    const unsigned short* Bg1 = Bt + (size_t)(n0 + (c1 >> 2)) * K + (c1 & 3) * 8;
    unsigned short* Asl0 = &As[w * 1024];
    unsigned short* Asl1 = &As[w * 1024 + 512];
    unsigned short* Bsl0 = &Bs[w * 1024];
    unsigned short* Bsl1 = &Bs[w * 1024 + 512];

    for (int k0 = 0; k0 < K; k0 += 32) {
        __builtin_amdgcn_global_load_lds(GLP(Ag0 + k0), LDP(Asl0), 16, 0, 0);
        __builtin_amdgcn_global_load_lds(GLP(Ag1 + k0), LDP(Asl1), 16, 0, 0);
        __builtin_amdgcn_global_load_lds(GLP(Bg0 + k0), LDP(Bsl0), 16, 0, 0);
        __builtin_amdgcn_global_load_lds(GLP(Bg1 + k0), LDP(Bsl1), 16, 0, 0);
        __syncthreads();
        const bf16x8* As8 = (const bf16x8*)As;
        const bf16x8* Bs8 = (const bf16x8*)Bs;
        bf16x8 af[4], bfr[4];
#pragma unroll
        for (int i = 0; i < 4; ++i) af[i] = As8[(wm + i * 16 + lm) * 4 + q];
#pragma unroll
        for (int j = 0; j < 4; ++j) bfr[j] = Bs8[(wn + j * 16 + lm) * 4 + q];
#pragma unroll
        for (int i = 0; i < 4; ++i)
#pragma unroll
            for (int j = 0; j < 4; ++j)
                acc[i][j] = __builtin_amdgcn_mfma_f32_16x16x32_bf16(
                    af[i], bfr[j], acc[i][j], 0, 0, 0);
        __syncthreads();
    }
#pragma unroll
    for (int j = 0; j < 4; ++j) {
        const int col = n0 + wn + j * 16 + lm;
        const float bj = bias[col];
#pragma unroll
        for (int i = 0; i < 4; ++i) {
            const int row = m0 + wm + i * 16 + q * 4;
#pragma unroll
            for (int r = 0; r < 4; ++r)
                C[(size_t)(row + r) * N + col] = f2bf(acc[i][j][r] + bj);
        }
    }
}

// ---------------------------------------------------------------------------
// Cacc[16, N] += X[16, K-slice] @ W[K-slice, N]   (atomic, C pre-zeroed)
// ---------------------------------------------------------------------------
#define KSL 128
__global__ __launch_bounds__(64) void gemm16(
    const float* __restrict__ X, const float* __restrict__ W,
    float* __restrict__ Cacc, int K, int N) {
    __shared__ __align__(16) float xs[16][KSL];
    const int tid = threadIdx.x;
    const int n = blockIdx.x * 64 + tid;
    const int k0 = blockIdx.y * KSL;
    for (int idx = tid; idx < 16 * KSL; idx += 64) {
        int b = idx >> 7;
        int k = idx & (KSL - 1);
        xs[b][k] = X[(size_t)b * K + k0 + k];
    }
    __syncthreads();
    float acc[16] = {};
    for (int k = 0; k < KSL; k += 4) {
        const float* wp = W + (size_t)(k0 + k) * N + n;
        float w0 = wp[0], w1 = wp[N], w2 = wp[2 * (size_t)N], w3 = wp[3 * (size_t)N];
#pragma unroll
        for (int b = 0; b < 16; ++b) {
            float4 xv = *(const float4*)&xs[b][k];
            acc[b] = fmaf(xv.x, w0, fmaf(xv.y, w1, fmaf(xv.z, w2, fmaf(xv.w, w3, acc[b]))));
        }
    }
#pragma unroll
    for (int b = 0; b < 16; ++b)
        atomicAdd(&Cacc[(size_t)b * N + n], acc[b]);
}

// ---------------------------------------------------------------------------
// Self-attention, one block per (h, b). Keys: cache[0..1022] + (k_new+bk).
// ---------------------------------------------------------------------------
__global__ __launch_bounds__(256) void attn_self(
    const float* __restrict__ q_raw, const float* __restrict__ bq,
    const float* __restrict__ kcache, const float* __restrict__ k_new,
    const float* __restrict__ bk,
    const float* __restrict__ vcache, const float* __restrict__ v_new,
    const float* __restrict__ bv, float* __restrict__ out) {
    const int h = blockIdx.x, b = blockIdx.y;
    const int tid = threadIdx.x;
    __shared__ __align__(16) float q[64];
    __shared__ float bks[64], bvs[64];
    __shared__ float sc[TTOT];
    __shared__ float red[256];
    if (tid < 64) {
        q[tid] = q_raw[b * DD + h * 64 + tid] + bq[h * 64 + tid];
        bks[tid] = bk[h * 64 + tid];
        bvs[tid] = bv[h * 64 + tid];
    }
    __syncthreads();
    const size_t bh = (size_t)(b * HH + h);
    for (int t = tid; t < TTOT; t += 256) {
        float dot = 0.f;
        if (t < TPAST) {
            const float4* kr = (const float4*)(kcache + (bh * TPAST + t) * HDIM);
            const float4* q4 = (const float4*)q;
#pragma unroll
            for (int i = 0; i < 16; ++i) {
                float4 kv = kr[i], qv = q4[i];
                dot += qv.x * kv.x + qv.y * kv.y + qv.z * kv.z + qv.w * kv.w;
            }
        } else {
            for (int i = 0; i < 64; ++i)
                dot += q[i] * (k_new[b * DD + h * 64 + i] + bks[i]);
        }
        sc[t] = dot * ASCALE;
    }
    __syncthreads();
    float lm = -1e30f;
    for (int t = tid; t < TTOT; t += 256) lm = fmaxf(lm, sc[t]);
    red[tid] = lm; __syncthreads();
    for (int s = 128; s > 0; s >>= 1) { if (tid < s) red[tid] = fmaxf(red[tid], red[tid + s]); __syncthreads(); }
    const float mx = red[0];
    __syncthreads();
    float ls = 0.f;
    for (int t = tid; t < TTOT; t += 256) { float p = __expf(sc[t] - mx); sc[t] = p; ls += p; }
    red[tid] = ls; __syncthreads();
    for (int s = 128; s > 0; s >>= 1) { if (tid < s) red[tid] += red[tid + s]; __syncthreads(); }
    const float inv = 1.0f / red[0];
    __syncthreads();
    const int hd = tid & 63, part = tid >> 6;
    float acc = 0.f;
    for (int t = part; t < TTOT; t += 4) {
        float v;
        if (t < TPAST) v = vcache[(bh * TPAST + t) * HDIM + hd];
        else           v = v_new[b * DD + h * 64 + hd] + bvs[hd];
        acc += sc[t] * v;
    }
    red[tid] = acc; __syncthreads();
    if (tid < 64)
        out[b * DD + h * 64 + tid] =
            (red[tid] + red[tid + 64] + red[tid + 128] + red[tid + 192]) * inv;
}

// ---------------------------------------------------------------------------
// Cross-attention vs precomputed bf16 Kc/Vc (biases already baked in).
// ---------------------------------------------------------------------------
__global__ __launch_bounds__(256) void attn_cross(
    const float* __restrict__ q_raw, const float* __restrict__ bq,
    const unsigned short* __restrict__ Kc, const unsigned short* __restrict__ Vc,
    float* __restrict__ out) {
    const int h = blockIdx.x, b = blockIdx.y;
    const int tid = threadIdx.x;
    __shared__ __align__(16) float q[64];
    __shared__ float sc[SENC];
    __shared__ float red[256];
    if (tid < 64)
        q[tid] = q_raw[b * DD + h * 64 + tid] + bq[h * 64 + tid];
    __syncthreads();
    for (int s = tid; s < SENC; s += 256) {
        const uint4* kr = (const uint4*)(Kc + ((size_t)(b * SENC + s)) * DD + h * HDIM);
        float dot = 0.f;
#pragma unroll
        for (int i = 0; i < 8; ++i) {
            uint4 u = kr[i];
            dot += q[i * 8 + 0] * bf2f((unsigned short)u.x) + q[i * 8 + 1] * bf2f((unsigned short)(u.x >> 16));
            dot += q[i * 8 + 2] * bf2f((unsigned short)u.y) + q[i * 8 + 3] * bf2f((unsigned short)(u.y >> 16));
            dot += q[i * 8 + 4] * bf2f((unsigned short)u.z) + q[i * 8 + 5] * bf2f((unsigned short)(u.z >> 16));
            dot += q[i * 8 + 6] * bf2f((unsigned short)u.w) + q[i * 8 + 7] * bf2f((unsigned short)(u.w >> 16));
        }
        sc[s] = dot * ASCALE;
    }
    __syncthreads();
    float lm = -1e30f;
    for (int t = tid; t < SENC; t += 256) lm = fmaxf(lm, sc[t]);
    red[tid] = lm; __syncthreads();
    for (int s = 128; s > 0; s >>= 1) { if (tid < s) red[tid] = fmaxf(red[tid], red[tid + s]); __syncthreads(); }
    const float mx = red[0];
    __syncthreads();
    float ls = 0.f;
    for (int t = tid; t < SENC; t += 256) { float p = __expf(sc[t] - mx); sc[t] = p; ls += p; }
    red[tid] = ls; __syncthreads();
    for (int s = 128; s > 0; s >>= 1) { if (tid < s) red[tid] += red[tid + s]; __syncthreads(); }
    const float inv = 1.0f / red[0];
    __syncthreads();
    const int hd = tid & 63, part = tid >> 6;
    float acc = 0.f;
    for (int t = part; t < SENC; t += 4)
        acc += sc[t] * bf2f(Vc[((size_t)(b * SENC + t)) * DD + h * HDIM + hd]);
    red[tid] = acc; __syncthreads();
    if (tid < 64)
        out[b * DD + h * 64 + tid] =
            (red[tid] + red[tid + 64] + red[tid + 128] + red[tid + 192]) * inv;
}

// ---------------------------------------------------------------------------
// x[b,:] = LN(x[b,:] + a[b,:] + abias) * g + bb   (one block per b)
// ---------------------------------------------------------------------------
__global__ __launch_bounds__(256) void ln_kernel(
    float* __restrict__ x, const float* __restrict__ a,
    const float* __restrict__ ab, const float* __restrict__ g,
    const float* __restrict__ bb) {
    const int b = blockIdx.x, tid = threadIdx.x;
    __shared__ float buf[DD];
    __shared__ float red[256];
    float ls = 0.f, lq = 0.f;
    for (int i = tid; i < DD; i += 256) {
        float v = x[b * DD + i] + a[b * DD + i] + ab[i];
        buf[i] = v; ls += v; lq += v * v;
    }
    red[tid] = ls; __syncthreads();
    for (int s = 128; s > 0; s >>= 1) { if (tid < s) red[tid] += red[tid + s]; __syncthreads(); }
    const float mean = red[0] * (1.0f / DD);
    __syncthreads();
    red[tid] = lq; __syncthreads();
    for (int s = 128; s > 0; s >>= 1) { if (tid < s) red[tid] += red[tid + s]; __syncthreads(); }
    const float var = red[0] * (1.0f / DD) - mean * mean;
    const float rstd = rsqrtf(var + LNEPS);
    for (int i = tid; i < DD; i += 256)
        x[b * DD + i] = (buf[i] - mean) * rstd * g[i] + bb[i];
}

__global__ __launch_bounds__(256) void relu_bias(
    const float* __restrict__ raw, const float* __restrict__ b1,
    float* __restrict__ out) {
    for (int i = blockIdx.x * 256 + threadIdx.x; i < BB * FFD; i += gridDim.x * 256)
        out[i] = fmaxf(0.f, raw[i] + b1[i & (FFD - 1)]);
}

// one block (64 threads) per (b, v) output logit
__global__ __launch_bounds__(64) void logits_kernel(
    const float* __restrict__ x, const float* __restrict__ w_out,
    const float* __restrict__ b_out, float* __restrict__ out) {
    const int b = blockIdx.x / VOUT, v = blockIdx.x % VOUT;
    const int tid = threadIdx.x;
    float acc = 0.f;
    for (int k = tid; k < DD; k += 64)
        acc += x[b * DD + k] * w_out[(size_t)k * VOUT + v];
    for (int s = 32; s > 0; s >>= 1) acc += __shfl_down(acc, s);
    if (tid == 0) out[b * VOUT + v] = acc + b_out[v];
}

extern "C" void kernel_launch(void* const* d_in, const int* in_sizes, int n_in,
                              void* d_out, int out_size, void* d_ws, size_t ws_size,
                              hipStream_t stream) {
    const float* x_in    = (const float*)d_in[0];
    const float* enc     = (const float*)d_in[1];
    const float* k_cache = (const float*)d_in[2];
    const float* v_cache = (const float*)d_in[3];
    const float* wq_s = (const float*)d_in[4];  const float* bq_s = (const float*)d_in[5];
    const float* wk_s = (const float*)d_in[6];  const float* bk_s = (const float*)d_in[7];
    const float* wv_s = (const float*)d_in[8];  const float* bv_s = (const float*)d_in[9];
    const float* wo_s = (const float*)d_in[10]; const float* bo_s = (const float*)d_in[11];
    const float* wq_c = (const float*)d_in[12]; const float* bq_c = (const float*)d_in[13];
    const float* wk_c = (const float*)d_in[14]; const float* bk_c = (const float*)d_in[15];
    const float* wv_c = (const float*)d_in[16]; const float* bv_c = (const float*)d_in[17];
    const float* wo_c = (const float*)d_in[18]; const float* bo_c = (const float*)d_in[19];
    const float* w1 = (const float*)d_in[20];   const float* b1 = (const float*)d_in[21];
    const float* w2 = (const float*)d_in[22];   const float* b2 = (const float*)d_in[23];
    const float* ln1_g = (const float*)d_in[24]; const float* ln1_b = (const float*)d_in[25];
    const float* ln2_g = (const float*)d_in[26]; const float* ln2_b = (const float*)d_in[27];
    const float* ln3_g = (const float*)d_in[28]; const float* ln3_b = (const float*)d_in[29];
    const float* w_out = (const float*)d_in[30]; const float* b_out = (const float*)d_in[31];
    float* out = (float*)d_out;

    float* ws = (float*)d_ws;
    float* x_buf  = ws;            // 16384
    float* mm_q   = ws + 16384;    // 16384
    float* mm_k   = ws + 32768;    // 16384
    float* mm_v   = ws + 49152;    // 16384
    float* attn_o = ws + 65536;    // 16384
    float* mm_p   = ws + 81920;    // 16384
    float* mm_h1  = ws + 98304;    // 65536
    float* h1a    = ws + 163840;   // 65536
    unsigned short* Abf = (unsigned short*)(ws + 229376);           // 16384x1024 bf16
    unsigned short* Wkt = Abf + (size_t)BB * SENC * DD;             // 1024x1024
    unsigned short* Wvt = Wkt + (size_t)DD * DD;
    unsigned short* Kc  = Wvt + (size_t)DD * DD;                    // 16384x1024
    unsigned short* Vc  = Kc + (size_t)BB * SENC * DD;

    hipMemcpyAsync(x_buf, x_in, (size_t)BB * DD * sizeof(float),
                   hipMemcpyDeviceToDevice, stream);

    // enc -> bf16 once
    cvt_bf16x4<<<(BB * SENC * DD / 4 + 255) / 256, 256, 0, stream>>>(
        enc, Abf, BB * SENC * DD / 4);

    const dim3 gBig(DD / 128, (BB * SENC) / 128);   // 8 x 128
    const dim3 gWt(16, 16);
    const dim3 gAttn(HH, BB);

    for (int l = 0; l < NLAYER; ++l) {
        const size_t oM = (size_t)l * DD * DD;
        const size_t oV = (size_t)l * DD;
        const size_t oC = (size_t)l * BB * HH * TPAST * HDIM;

        // cross-attn K/V projections for this layer (bias baked in, MFMA)
        wt_bf16<<<gWt, 256, 0, stream>>>(wk_c + oM, Wkt);
        wt_bf16<<<gWt, 256, 0, stream>>>(wv_c + oM, Wvt);
        gemm_mfma_bt<<<gBig, 256, 0, stream>>>(Abf, Wkt, bk_c + oV, Kc);
        gemm_mfma_bt<<<gBig, 256, 0, stream>>>(Abf, Wvt, bv_c + oV, Vc);

        // ---- self attention ----
        hipMemsetAsync(mm_q, 0, 3 * (size_t)BB * DD * sizeof(float), stream);
        gemm16<<<dim3(DD / 64, DD / KSL), 64, 0, stream>>>(x_buf, wq_s + oM, mm_q, DD, DD);
        gemm16<<<dim3(DD / 64, DD / KSL), 64, 0, stream>>>(x_buf, wk_s + oM, mm_k, DD, DD);
        gemm16<<<dim3(DD / 64, DD / KSL), 64, 0, stream>>>(x_buf, wv_s + oM, mm_v, DD, DD);
        attn_self<<<gAttn, 256, 0, stream>>>(mm_q, bq_s + oV, k_cache + oC, mm_k,
                                             bk_s + oV, v_cache + oC, mm_v, bv_s + oV,
                                             attn_o);
        hipMemsetAsync(mm_p, 0, (size_t)BB * DD * sizeof(float), stream);
        gemm16<<<dim3(DD / 64, DD / KSL), 64, 0, stream>>>(attn_o, wo_s + oM, mm_p, DD, DD);
        ln_kernel<<<BB, 256, 0, stream>>>(x_buf, mm_p, bo_s + oV, ln1_g + oV, ln1_b + oV);

        // ---- cross attention ----
        hipMemsetAsync(mm_q, 0, (size_t)BB * DD * sizeof(float), stream);
        gemm16<<<dim3(DD / 64, DD / KSL), 64, 0, stream>>>(x_buf, wq_c + oM, mm_q, DD, DD);
        attn_cross<<<gAttn, 256, 0, stream>>>(mm_q, bq_c + oV, Kc, Vc, attn_o);
        hipMemsetAsync(mm_p, 0, (size_t)BB * DD * sizeof(float), stream);
        gemm16<<<dim3(DD / 64, DD / KSL), 64, 0, stream>>>(attn_o, wo_c + oM, mm_p, DD, DD);
        ln_kernel<<<BB, 256, 0, stream>>>(x_buf, mm_p, bo_c + oV, ln2_g + oV, ln2_b + oV);

        // ---- FFN ----
        hipMemsetAsync(mm_h1, 0, (size_t)BB * FFD * sizeof(float), stream);
        gemm16<<<dim3(FFD / 64, DD / KSL), 64, 0, stream>>>(x_buf, w1 + (size_t)l * DD * FFD,
                                                            mm_h1, DD, FFD);
        relu_bias<<<64, 256, 0, stream>>>(mm_h1, b1 + (size_t)l * FFD, h1a);
        hipMemsetAsync(mm_p, 0, (size_t)BB * DD * sizeof(float), stream);
        gemm16<<<dim3(DD / 64, FFD / KSL), 64, 0, stream>>>(h1a, w2 + (size_t)l * FFD * DD,
                                                            mm_p, FFD, DD);
        ln_kernel<<<BB, 256, 0, stream>>>(x_buf, mm_p, b2 + oV, ln3_g + oV, ln3_b + oV);
    }

    logits_kernel<<<BB * VOUT, 64, 0, stream>>>(x_buf, w_out, b_out, out);
}